// Round 2
// baseline (324.786 us; speedup 1.0000x reference)
//
#include <hip/hip_runtime.h>
#include <float.h>

#define K_NN 10
#define BATCH 8
#define CIN 6
#define NPTS 4096
#define COUT 64
#define NSEG 8
#define SEGLEN (NPTS / NSEG)    // 512
#define CHUNK 16
#define QB 64                   // queries per knn block
#define WPB 4                   // waves per knn block
#define QSEG (SEGLEN / WPB)     // 128 candidate points per wave
#define QCH (QSEG / CHUNK)      // 8 chunks per wave
#define NCHT (WPB * QCH)        // 32 chunk maxima per (query, segment)
#define NWORDW (QSEG / 32)      // 4 mask words per wave
#define NEG_SLOPE 0.2f
#define BN_EPS 1e-5f

// ---- workspace layout (bytes) ----
// part[] aliases q[]: part is fully consumed by merge_kernel before feat_kernel writes q.
static constexpr size_t OFF_IDX = 0;                                                   // int[8*10*4096]  (plane layout [b][j][n])
static constexpr size_t OFF_PTS = OFF_IDX + (size_t)BATCH * K_NN * NPTS * sizeof(int); // float4[8*4096]
static constexpr size_t OFF_Q   = OFF_PTS + (size_t)BATCH * NPTS * sizeof(float4);     // alias: q / part
static constexpr size_t SZ_Q    = (size_t)NSEG * BATCH * NPTS * K_NN * sizeof(int);    // 10.49 MB
static constexpr size_t OFF_ST  = OFF_Q + SZ_Q;                                        // double[27]

__device__ __forceinline__ float wave_sum(float v) {
#pragma unroll
    for (int m = 32; m >= 1; m >>= 1) v += __shfl_xor(v, m, 64);
    return v;
}
__device__ __forceinline__ float wave_max(float v) {
#pragma unroll
    for (int m = 32; m >= 1; m >>= 1) v = fmaxf(v, __shfl_xor(v, m, 64));
    return v;
}

// pts stores (2x, 2y, 2z, ||p||^2); query coords pre-halved once per thread.
// d' = 2*inner - ||c||^2 -> exactly 3 FMAs. Monotone shift of true distance,
// used consistently in knn_part/drain/merge.
__device__ __forceinline__ float distp(float qx, float qy, float qz, float4 c) {
    return fmaf(c.x, qx, fmaf(c.y, qy, fmaf(c.z, qz, -c.w)));
}

// ---- Kernel P: pack (2x,2y,2z,||p||^2) per point; block 0 zeroes stats ----
__global__ __launch_bounds__(256) void prep_pts(const float* __restrict__ x,
                                                float4* __restrict__ pts,
                                                double* __restrict__ stats) {
    if (blockIdx.x == 0 && threadIdx.x < 27) stats[threadIdx.x] = 0.0;
    int t = blockIdx.x * 256 + threadIdx.x;   // 0..32767
    int b = t >> 12;
    int n = t & (NPTS - 1);
    const float* xb = x + (size_t)b * CIN * NPTS;
    float x0 = xb[n];
    float x1 = xb[NPTS + n];
    float x2 = xb[2 * NPTS + n];
    pts[t] = make_float4(2.0f * x0, 2.0f * x1, 2.0f * x2, x0 * x0 + x1 * x1 + x2 * x2);
}

// ---- Kernel A1: per-segment exact top-10, 4-wave cooperative ----
// Block = 4 waves over the SAME 64 queries; wave w scans quarter-segment w.
//   ph1: each wave -> 8 chunk maxima per query -> LDS.
//   wave 0: 10-chain over all 32 maxima -> thr (IDENTICAL value to the
//           single-wave version: 10th largest of the same 32 chunk maxima).
//   ph2: each wave mask-filters its quarter (d >= thr), drains quarter top-10.
//   wave 1: merges 4x10 (w asc, j asc == candidate-index asc -> same tie
//           semantics as a single ascending scan) -> segment top-10 -> part.
// Exactness: thr <= v10(segment) (10 distinct chunks each hold >=1 elem >= thr);
// any segment-top-10 member is in its quarter's top-10 (prefix property).
__global__ __launch_bounds__(256, 6) void knn_part(const float4* __restrict__ pts,
                                                   int* __restrict__ part) {
    // union: cmax[32][64] (8 KB) reused by dml[40][64] (10 KB) + iml[40][64] u16 (5 KB)
    __shared__ alignas(16) char smem[(WPB * K_NN) * QB * (sizeof(float) + sizeof(unsigned short))];
    __shared__ float thrS[QB];
    float (*cmax)[QB] = (float (*)[QB])smem;                      // [NCHT][QB]
    float (*dml)[QB]  = (float (*)[QB])smem;                      // [WPB*K_NN][QB]
    unsigned short (*iml)[QB] =
        (unsigned short (*)[QB])(smem + (WPB * K_NN) * QB * sizeof(float));

    int b  = blockIdx.y;
    int s  = blockIdx.z;
    int ln = threadIdx.x & 63;
    int wv = threadIdx.x >> 6;
    int n  = blockIdx.x * QB + ln;
    const float4* p = pts + (size_t)b * NPTS;   // wave-uniform base
    float4 q4 = p[n];
    float qx = 0.5f * q4.x, qy = 0.5f * q4.y, qz = 0.5f * q4.z;

    int m0 = s * SEGLEN;
    int mw = m0 + wv * QSEG;                    // this wave's quarter

    // ---- phase 1: chunk maxima for this wave's quarter ----
    for (int ch = 0; ch < QCH; ch++) {
        const float4* cp = p + (mw + ch * CHUNK);
        float cm = distp(qx, qy, qz, cp[0]);
#pragma unroll
        for (int u = 1; u < CHUNK; u++) cm = fmaxf(cm, distp(qx, qy, qz, cp[u]));
        cmax[wv * QCH + ch][ln] = cm;
    }
    __syncthreads();

    // ---- wave 0: threshold = 10th largest of 32 chunk maxima ----
    if (wv == 0) {
        float vals[K_NN];
#pragma unroll
        for (int j = 0; j < K_NN; j++) vals[j] = -FLT_MAX;
        for (int c = 0; c < NCHT; c++) {
            float t = cmax[c][ln];
#pragma unroll
            for (int j = 0; j < K_NN; j++) {
                float hi = fmaxf(vals[j], t);
                t = fminf(vals[j], t);
                vals[j] = hi;
            }
        }
        thrS[ln] = vals[K_NN - 1];
    }
    __syncthreads();
    float thr = thrS[ln];

    // ---- phase 2 + drain: bitmask survivors in this quarter, exact insert ----
    float fv[K_NN];
    int fi[K_NN];
#pragma unroll
    for (int j = 0; j < K_NN; j++) { fv[j] = -FLT_MAX; fi[j] = 0; }

    for (int w = 0; w < NWORDW; w++) {
        const float4* cp = p + (mw + w * 32);
        unsigned int mask = 0u;
#pragma unroll
        for (int u = 0; u < 32; u++) {
            float d = distp(qx, qy, qz, cp[u]);
            mask = (mask << 1) | (d >= thr ? 1u : 0u);   // point u -> bit (31-u)
        }
        int base = mw + w * 32;
        while (mask) {
            int j = __builtin_clz(mask);        // MSB-first == ascending m
            mask ^= (0x80000000u >> j);
            int m = base + j;
            float4 c = p[m];                    // L1-hot (quarter = 2 KB)
            float d = distp(qx, qy, qz, c);
            if (d > fv[K_NN - 1]) {
                fv[K_NN - 1] = d;
                fi[K_NN - 1] = m;
#pragma unroll
                for (int t2 = K_NN - 1; t2 > 0; t2--) {
                    if (fv[t2] > fv[t2 - 1]) {
                        float tv = fv[t2]; fv[t2] = fv[t2 - 1]; fv[t2 - 1] = tv;
                        int ti = fi[t2]; fi[t2] = fi[t2 - 1]; fi[t2 - 1] = ti;
                    }
                }
            }
        }
    }

    // publish quarter lists (overwrites cmax region; wave0 finished its reads
    // before the sync above)
#pragma unroll
    for (int j = 0; j < K_NN; j++) {
        dml[wv * K_NN + j][ln] = fv[j];
        iml[wv * K_NN + j][ln] = (unsigned short)fi[j];
    }
    __syncthreads();

    // ---- wave 1: merge 4x10 -> segment top-10, write part ----
    if (wv == 1) {
        float gv[K_NN];
        int gi[K_NN];
#pragma unroll
        for (int j = 0; j < K_NN; j++) { gv[j] = -FLT_MAX; gi[j] = 0; }
#pragma unroll
        for (int w2 = 0; w2 < WPB; w2++) {
#pragma unroll
            for (int j = 0; j < K_NN; j++) {
                float d = dml[w2 * K_NN + j][ln];
                int m = iml[w2 * K_NN + j][ln];
                if (d > gv[K_NN - 1]) {
                    gv[K_NN - 1] = d;
                    gi[K_NN - 1] = m;
#pragma unroll
                    for (int t2 = K_NN - 1; t2 > 0; t2--) {
                        if (gv[t2] > gv[t2 - 1]) {
                            float tv = gv[t2]; gv[t2] = gv[t2 - 1]; gv[t2 - 1] = tv;
                            int ti = gi[t2]; gi[t2] = gi[t2 - 1]; gi[t2 - 1] = ti;
                        }
                    }
                }
            }
        }
        int* o = part + (((size_t)s * BATCH + b) * K_NN) * NPTS + n;
#pragma unroll
        for (int j = 0; j < K_NN; j++) o[(size_t)j * NPTS] = gi[j];
    }
}

// ---- Kernel A2: merge 8 segment lists -> global top-10 (re-evaluates 80 cands) ----
__global__ __launch_bounds__(64) void merge_kernel(const float4* __restrict__ pts,
                                                   const int* __restrict__ part,
                                                   int* __restrict__ idxo) {
    int b = blockIdx.y;
    int n = blockIdx.x * 64 + threadIdx.x;
    const float4* p = pts + (size_t)b * NPTS;
    float4 q4 = p[n];
    float qx = 0.5f * q4.x, qy = 0.5f * q4.y, qz = 0.5f * q4.z;

    float vals[K_NN];
    int inds[K_NN];
#pragma unroll
    for (int j = 0; j < K_NN; j++) { vals[j] = -FLT_MAX; inds[j] = 0; }

#pragma unroll
    for (int s = 0; s < NSEG; s++) {
        const int* pp = part + (((size_t)s * BATCH + b) * K_NN) * NPTS + n;
#pragma unroll
        for (int j = 0; j < K_NN; j++) {
            int m = pp[(size_t)j * NPTS];
            float4 c = p[m];                     // divergent but L1/L2-resident
            float d = distp(qx, qy, qz, c);
            if (d > vals[K_NN - 1]) {
                vals[K_NN - 1] = d;
                inds[K_NN - 1] = m;
#pragma unroll
                for (int t = K_NN - 1; t > 0; t--) {
                    if (vals[t] > vals[t - 1]) {
                        float tv = vals[t]; vals[t] = vals[t - 1]; vals[t - 1] = tv;
                        int ti = inds[t]; inds[t] = inds[t - 1]; inds[t - 1] = ti;
                    }
                }
            }
        }
    }

    // plane layout [b][j][n] : coalesced write, coalesced read in feat
    int* o = idxo + (size_t)b * K_NN * NPTS + n;
#pragma unroll
    for (int j = 0; j < K_NN; j++) o[(size_t)j * NPTS] = inds[j];
}

// ---- Kernel B: gather + center + q[b,o,n] = max_k (W feat) + moment stats ----
__global__ __launch_bounds__(128) void feat_kernel(const float4* __restrict__ pts,
                                                   const float* __restrict__ x,
                                                   const float* __restrict__ W,
                                                   const int* __restrict__ idx,
                                                   float* __restrict__ q,
                                                   double* __restrict__ stats) {
    __shared__ float sW[COUT * CIN];
    __shared__ float sred[2][27];
    for (int i = threadIdx.x; i < COUT * CIN; i += 128) sW[i] = W[i];
    __syncthreads();

    int b = blockIdx.y;
    int n = blockIdx.x * 128 + threadIdx.x;
    const float* xb = x + (size_t)b * CIN * NPTS;
    const float4* p = pts + (size_t)b * NPTS;

    int nb[K_NN];
#pragma unroll
    for (int k = 0; k < K_NN; k++) nb[k] = idx[((size_t)b * K_NN + k) * NPTS + n];

    float f[CIN][K_NN];
#pragma unroll
    for (int k = 0; k < K_NN; k++) {
        float4 c = p[nb[k]];                    // xyz in one 16B gather (doubled)
        f[0][k] = 0.5f * c.x; f[1][k] = 0.5f * c.y; f[2][k] = 0.5f * c.z;
    }
#pragma unroll
    for (int c = 3; c < CIN; c++)
#pragma unroll
        for (int k = 0; k < K_NN; k++)
            f[c][k] = xb[c * NPTS + nb[k]];

    // center xyz over k, scale by 10
#pragma unroll
    for (int c = 0; c < 3; c++) {
        float s = 0.f;
#pragma unroll
        for (int k = 0; k < K_NN; k++) s += f[c][k];
        float m = s / 10.0f;
#pragma unroll
        for (int k = 0; k < K_NN; k++) f[c][k] = (f[c][k] - m) * 10.0f;
    }

    // q[b,o,n] = max_k y (BN affine + leaky are monotone -> applied in reduce)
    float* qb = q + (size_t)b * COUT * NPTS + n;
#pragma unroll
    for (int o = 0; o < COUT; o++) {
        float w0 = sW[o * 6 + 0], w1 = sW[o * 6 + 1], w2 = sW[o * 6 + 2];
        float w3 = sW[o * 6 + 3], w4 = sW[o * 6 + 4], w5 = sW[o * 6 + 5];
        float mx = -FLT_MAX;
#pragma unroll
        for (int k = 0; k < K_NN; k++) {
            float y = w0 * f[0][k] + w1 * f[1][k] + w2 * f[2][k] +
                      w3 * f[3][k] + w4 * f[4][k] + w5 * f[5][k];
            mx = fmaxf(mx, y);
        }
        qb[(size_t)o * NPTS] = mx;
    }

    // moment stats: S1[6], S2[21]
    float s1[CIN];
#pragma unroll
    for (int c = 0; c < CIN; c++) {
        float s = 0.f;
#pragma unroll
        for (int k = 0; k < K_NN; k++) s += f[c][k];
        s1[c] = s;
    }
    float s2[21];
#pragma unroll
    for (int i = 0; i < 21; i++) s2[i] = 0.f;
#pragma unroll
    for (int k = 0; k < K_NN; k++) {
        int pp = 0;
#pragma unroll
        for (int c = 0; c < CIN; c++)
#pragma unroll
            for (int c2 = c; c2 < CIN; c2++) {
                s2[pp] += f[c][k] * f[c2][k];
                pp++;
            }
    }
#pragma unroll
    for (int c = 0; c < CIN; c++) s1[c] = wave_sum(s1[c]);
#pragma unroll
    for (int i = 0; i < 21; i++) s2[i] = wave_sum(s2[i]);

    int wv = threadIdx.x >> 6;
    int ln = threadIdx.x & 63;
    if (ln == 0) {
#pragma unroll
        for (int c = 0; c < CIN; c++) sred[wv][c] = s1[c];
#pragma unroll
        for (int i = 0; i < 21; i++) sred[wv][6 + i] = s2[i];
    }
    __syncthreads();
    if (threadIdx.x < 27) {
        float t = sred[0][threadIdx.x] + sred[1][threadIdx.x];
        atomicAdd(&stats[threadIdx.x], (double)t);
    }
}

// ---- Kernel C: fold moments -> scale/shift (in-block); leaky; reduce max+mean ----
__global__ __launch_bounds__(256) void reduce_kernel(const float* __restrict__ q,
                                                     const double* __restrict__ stats,
                                                     const float* __restrict__ W,
                                                     const float* __restrict__ gamma,
                                                     const float* __restrict__ beta,
                                                     float* __restrict__ out) {
    int o = blockIdx.x;
    int b = blockIdx.y;

    __shared__ float s_sc, s_sh;
    if (threadIdx.x == 0) {
        const double minv = 1.0 / (double)((size_t)BATCH * NPTS * K_NN);
        double w[CIN];
#pragma unroll
        for (int c = 0; c < CIN; c++) w[c] = (double)W[o * CIN + c];
        double mu = 0.0;
#pragma unroll
        for (int c = 0; c < CIN; c++) mu += w[c] * stats[c];
        mu *= minv;
        double ey2 = 0.0;
        int pp = 6;
#pragma unroll
        for (int c = 0; c < CIN; c++)
#pragma unroll
            for (int c2 = c; c2 < CIN; c2++) {
                double v = w[c] * w[c2] * stats[pp];
                ey2 += (c2 == c) ? v : 2.0 * v;
                pp++;
            }
        ey2 *= minv;
        double var = ey2 - mu * mu;
        float scale = gamma[o] * rsqrtf((float)var + BN_EPS);
        float shift = beta[o] - (float)mu * scale;
        s_sc = scale;
        s_sh = shift;
    }
    __syncthreads();
    float scale = s_sc, shift = s_sh;

    const float* qp = q + ((size_t)b * COUT + o) * NPTS;
    float mx = -FLT_MAX, sm = 0.f;
    for (int i = threadIdx.x; i < NPTS; i += 256) {
        float z = scale * qp[i] + shift;
        z = (z >= 0.f) ? z : NEG_SLOPE * z;
        mx = fmaxf(mx, z);
        sm += z;
    }
    mx = wave_max(mx);
    sm = wave_sum(sm);
    __shared__ float smx[4], ssm2[4];
    int wv = threadIdx.x >> 6;
    int ln = threadIdx.x & 63;
    if (ln == 0) { smx[wv] = mx; ssm2[wv] = sm; }
    __syncthreads();
    if (threadIdx.x == 0) {
        float m = fmaxf(fmaxf(smx[0], smx[1]), fmaxf(smx[2], smx[3]));
        float s = ssm2[0] + ssm2[1] + ssm2[2] + ssm2[3];
        out[b * 2 * COUT + o] = m;
        out[b * 2 * COUT + COUT + o] = s * (1.0f / (float)NPTS);
    }
}

extern "C" void kernel_launch(void* const* d_in, const int* in_sizes, int n_in,
                              void* d_out, int out_size, void* d_ws, size_t ws_size,
                              hipStream_t stream) {
    const float* x     = (const float*)d_in[0];
    const float* W     = (const float*)d_in[1];
    const float* gamma = (const float*)d_in[2];
    const float* beta  = (const float*)d_in[3];
    float* out = (float*)d_out;

    char* ws = (char*)d_ws;
    int*    idx   = (int*)(ws + OFF_IDX);
    float4* pts   = (float4*)(ws + OFF_PTS);
    int*    part  = (int*)(ws + OFF_Q);     // aliases q region (consumed before q written)
    float*  q     = (float*)(ws + OFF_Q);
    double* stats = (double*)(ws + OFF_ST);

    prep_pts<<<BATCH * NPTS / 256, 256, 0, stream>>>(x, pts, stats);
    knn_part<<<dim3(NPTS / QB, BATCH, NSEG), 256, 0, stream>>>(pts, part);
    merge_kernel<<<dim3(NPTS / 64, BATCH), 64, 0, stream>>>(pts, part, idx);
    feat_kernel<<<dim3(NPTS / 128, BATCH), 128, 0, stream>>>(pts, x, W, idx, q, stats);
    reduce_kernel<<<dim3(COUT, BATCH), 256, 0, stream>>>(q, stats, W, gamma, beta, out);
}

// Round 3
// 202.406 us; speedup vs baseline: 1.6046x; 1.6046x over previous
//
#include <hip/hip_runtime.h>
#include <float.h>

#define K_NN 10
#define BATCH 8
#define CIN 6
#define NPTS 4096
#define COUT 64
#define NSEG 8
#define SEGLEN (NPTS / NSEG)    // 512
#define CHUNK 16
#define QB 64                   // queries per knn block
#define WPB 4                   // waves per knn block
#define QSEG (SEGLEN / WPB)     // 128 candidate points per wave
#define QCH (QSEG / CHUNK)      // 8 chunks per wave
#define NCHT (WPB * QCH)        // 32 chunk maxima per (query, segment)
#define NWORDW (QSEG / 32)      // 4 mask words per wave
#define NEG_SLOPE 0.2f
#define BN_EPS 1e-5f

// ---- workspace layout (bytes) ----
// part[] aliases q[]: part is fully consumed by merge_kernel before feat_kernel writes q.
static constexpr size_t OFF_IDX = 0;                                                   // int[8*10*4096]  (plane layout [b][j][n])
static constexpr size_t OFF_PTS = OFF_IDX + (size_t)BATCH * K_NN * NPTS * sizeof(int); // float4[8*4096]
static constexpr size_t OFF_Q   = OFF_PTS + (size_t)BATCH * NPTS * sizeof(float4);     // alias: q / part
static constexpr size_t SZ_Q    = (size_t)NSEG * BATCH * NPTS * K_NN * sizeof(int);    // 10.49 MB
static constexpr size_t OFF_ST  = OFF_Q + SZ_Q;                                        // double[27]

__device__ __forceinline__ float wave_sum(float v) {
#pragma unroll
    for (int m = 32; m >= 1; m >>= 1) v += __shfl_xor(v, m, 64);
    return v;
}
__device__ __forceinline__ float wave_max(float v) {
#pragma unroll
    for (int m = 32; m >= 1; m >>= 1) v = fmaxf(v, __shfl_xor(v, m, 64));
    return v;
}

// pts stores (2x, 2y, 2z, ||p||^2); query coords pre-halved once per thread.
// d' = 2*inner - ||c||^2 -> exactly 3 FMAs. Monotone shift of true distance,
// used consistently in knn_part/drain/merge.
__device__ __forceinline__ float distp(float qx, float qy, float qz, float4 c) {
    return fmaf(c.x, qx, fmaf(c.y, qy, fmaf(c.z, qz, -c.w)));
}

__device__ __forceinline__ float fmax3(float a, float b, float c) {
    return fmaxf(fmaxf(a, b), c);   // fuses to v_max3_f32 (exact for non-NaN)
}

// ---- Kernel P: pack (2x,2y,2z,||p||^2) per point; block 0 zeroes stats ----
__global__ __launch_bounds__(256) void prep_pts(const float* __restrict__ x,
                                                float4* __restrict__ pts,
                                                double* __restrict__ stats) {
    if (blockIdx.x == 0 && threadIdx.x < 27) stats[threadIdx.x] = 0.0;
    int t = blockIdx.x * 256 + threadIdx.x;   // 0..32767
    int b = t >> 12;
    int n = t & (NPTS - 1);
    const float* xb = x + (size_t)b * CIN * NPTS;
    float x0 = xb[n];
    float x1 = xb[NPTS + n];
    float x2 = xb[2 * NPTS + n];
    pts[t] = make_float4(2.0f * x0, 2.0f * x1, 2.0f * x2, x0 * x0 + x1 * x1 + x2 * x2);
}

// ---- Kernel A1: per-segment exact top-10, 4-wave cooperative ----
// Block = 4 waves over the SAME 64 queries; wave w scans quarter-segment w.
// CRITICAL (round-2 lesson): the quarter base must be compiler-UNIFORM so the
// candidate loads stay scalar (s_load_dwordx4). wv is wave-uniform in fact;
// readfirstlane makes it uniform in the divergence analysis. Round 2 lost this
// (SGPR 96->32, VGPR 24->40) and knn went 76->172 us from per-lane gathers.
//   ph1: each wave -> 8 chunk maxima per query -> LDS.
//   wave 0: 10-chain over all 32 maxima -> thr (same VALUE as single-wave:
//           10th largest of the same 32 chunk maxima, order-independent).
//   ph2: each wave mask-filters its quarter (d >= thr), drains quarter top-10.
//   wave 1: merges 4x10 (w asc, j asc == candidate-index asc -> same tie
//           semantics as a single ascending scan) -> segment top-10 -> part.
// Exactness: thr <= v10(segment) (10 distinct chunks each hold >=1 elem >= thr);
// any segment-top-10 member is in its quarter's top-10 (prefix property).
__global__ __launch_bounds__(256, 8) void knn_part(const float4* __restrict__ pts,
                                                   int* __restrict__ part) {
    // union: cmax[32][64] (8 KB) reused by dml[40][64] (10 KB) + iml[40][64] u16 (5 KB)
    __shared__ alignas(16) char smem[(WPB * K_NN) * QB * (sizeof(float) + sizeof(unsigned short))];
    __shared__ float thrS[QB];
    float (*cmax)[QB] = (float (*)[QB])smem;                      // [NCHT][QB]
    float (*dml)[QB]  = (float (*)[QB])smem;                      // [WPB*K_NN][QB]
    unsigned short (*iml)[QB] =
        (unsigned short (*)[QB])(smem + (WPB * K_NN) * QB * sizeof(float));

    int b  = blockIdx.y;
    int s  = blockIdx.z;
    int ln = threadIdx.x & 63;
    int wv = threadIdx.x >> 6;
    int wvu = __builtin_amdgcn_readfirstlane(wv);   // wave-uniform in SGPR
    int n  = blockIdx.x * QB + ln;
    const float4* p = pts + (size_t)b * NPTS;   // uniform base -> scalar loads
    float4 q4 = p[n];
    float qx = 0.5f * q4.x, qy = 0.5f * q4.y, qz = 0.5f * q4.z;

    int m0 = s * SEGLEN;
    int mw = m0 + wvu * QSEG;                   // UNIFORM quarter base

    // ---- phase 1: chunk maxima for this wave's quarter (scalar loads) ----
    for (int ch = 0; ch < QCH; ch++) {
        const float4* cp = p + (mw + ch * CHUNK);
        float d[CHUNK];
#pragma unroll
        for (int u = 0; u < CHUNK; u++) d[u] = distp(qx, qy, qz, cp[u]);
        float a0 = fmax3(d[0], d[1], d[2]);
        float a1 = fmax3(d[3], d[4], d[5]);
        float a2 = fmax3(d[6], d[7], d[8]);
        float a3 = fmax3(d[9], d[10], d[11]);
        float a4 = fmax3(d[12], d[13], d[14]);
        cmax[wv * QCH + ch][ln] = fmaxf(fmax3(fmax3(a0, a1, a2), a3, a4), d[15]);
    }
    __syncthreads();

    // ---- wave 0: threshold = 10th largest of 32 chunk maxima ----
    if (wvu == 0) {
        float vals[K_NN];
#pragma unroll
        for (int j = 0; j < K_NN; j++) vals[j] = -FLT_MAX;
        for (int c = 0; c < NCHT; c++) {
            float t = cmax[c][ln];
#pragma unroll
            for (int j = 0; j < K_NN; j++) {
                float hi = fmaxf(vals[j], t);
                t = fminf(vals[j], t);
                vals[j] = hi;
            }
        }
        thrS[ln] = vals[K_NN - 1];
    }
    __syncthreads();
    float thr = thrS[ln];

    // ---- phase 2 + drain: bitmask survivors in this quarter, exact insert ----
    float fv[K_NN];
    int fi[K_NN];
#pragma unroll
    for (int j = 0; j < K_NN; j++) { fv[j] = -FLT_MAX; fi[j] = 0; }

    for (int w = 0; w < NWORDW; w++) {
        const float4* cp = p + (mw + w * 32);   // uniform -> scalar loads
        unsigned int mask = 0u;
#pragma unroll
        for (int u = 0; u < 32; u++) {
            float d = distp(qx, qy, qz, cp[u]);
            mask = (mask << 1) | (d >= thr ? 1u : 0u);   // point u -> bit (31-u)
        }
        int base = mw + w * 32;
        while (mask) {
            int j = __builtin_clz(mask);        // MSB-first == ascending m
            mask ^= (0x80000000u >> j);
            int m = base + j;
            float4 c = p[m];                    // divergent, L1-hot (quarter = 2 KB)
            float d = distp(qx, qy, qz, c);
            if (d > fv[K_NN - 1]) {
                fv[K_NN - 1] = d;
                fi[K_NN - 1] = m;
#pragma unroll
                for (int t2 = K_NN - 1; t2 > 0; t2--) {
                    if (fv[t2] > fv[t2 - 1]) {
                        float tv = fv[t2]; fv[t2] = fv[t2 - 1]; fv[t2 - 1] = tv;
                        int ti = fi[t2]; fi[t2] = fi[t2 - 1]; fi[t2 - 1] = ti;
                    }
                }
            }
        }
    }

    // publish quarter lists (overwrites cmax region; wave0 finished its reads
    // before the sync above)
#pragma unroll
    for (int j = 0; j < K_NN; j++) {
        dml[wv * K_NN + j][ln] = fv[j];
        iml[wv * K_NN + j][ln] = (unsigned short)fi[j];
    }
    __syncthreads();

    // ---- wave 1: merge 4x10 -> segment top-10, write part ----
    if (wvu == 1) {
        float gv[K_NN];
        int gi[K_NN];
#pragma unroll
        for (int j = 0; j < K_NN; j++) { gv[j] = -FLT_MAX; gi[j] = 0; }
#pragma unroll
        for (int w2 = 0; w2 < WPB; w2++) {
#pragma unroll
            for (int j = 0; j < K_NN; j++) {
                float d = dml[w2 * K_NN + j][ln];
                int m = iml[w2 * K_NN + j][ln];
                if (d > gv[K_NN - 1]) {
                    gv[K_NN - 1] = d;
                    gi[K_NN - 1] = m;
#pragma unroll
                    for (int t2 = K_NN - 1; t2 > 0; t2--) {
                        if (gv[t2] > gv[t2 - 1]) {
                            float tv = gv[t2]; gv[t2] = gv[t2 - 1]; gv[t2 - 1] = tv;
                            int ti = gi[t2]; gi[t2] = gi[t2 - 1]; gi[t2 - 1] = ti;
                        }
                    }
                }
            }
        }
        int* o = part + (((size_t)s * BATCH + b) * K_NN) * NPTS + n;
#pragma unroll
        for (int j = 0; j < K_NN; j++) o[(size_t)j * NPTS] = gi[j];
    }
}

// ---- Kernel A2: merge 8 segment lists -> global top-10 (re-evaluates 80 cands) ----
__global__ __launch_bounds__(256) void merge_kernel(const float4* __restrict__ pts,
                                                    const int* __restrict__ part,
                                                    int* __restrict__ idxo) {
    int b = blockIdx.y;
    int n = blockIdx.x * 256 + threadIdx.x;
    const float4* p = pts + (size_t)b * NPTS;
    float4 q4 = p[n];
    float qx = 0.5f * q4.x, qy = 0.5f * q4.y, qz = 0.5f * q4.z;

    float vals[K_NN];
    int inds[K_NN];
#pragma unroll
    for (int j = 0; j < K_NN; j++) { vals[j] = -FLT_MAX; inds[j] = 0; }

#pragma unroll
    for (int s = 0; s < NSEG; s++) {
        const int* pp = part + (((size_t)s * BATCH + b) * K_NN) * NPTS + n;
#pragma unroll
        for (int j = 0; j < K_NN; j++) {
            int m = pp[(size_t)j * NPTS];
            float4 c = p[m];                     // divergent but L1/L2-resident
            float d = distp(qx, qy, qz, c);
            if (d > vals[K_NN - 1]) {
                vals[K_NN - 1] = d;
                inds[K_NN - 1] = m;
#pragma unroll
                for (int t = K_NN - 1; t > 0; t--) {
                    if (vals[t] > vals[t - 1]) {
                        float tv = vals[t]; vals[t] = vals[t - 1]; vals[t - 1] = tv;
                        int ti = inds[t]; inds[t] = inds[t - 1]; inds[t - 1] = ti;
                    }
                }
            }
        }
    }

    // plane layout [b][j][n] : coalesced write, coalesced read in feat
    int* o = idxo + (size_t)b * K_NN * NPTS + n;
#pragma unroll
    for (int j = 0; j < K_NN; j++) o[(size_t)j * NPTS] = inds[j];
}

// ---- Kernel B: gather + center + q[b,o,n] = max_k (W feat) + moment stats ----
__global__ __launch_bounds__(256) void feat_kernel(const float4* __restrict__ pts,
                                                   const float* __restrict__ x,
                                                   const float* __restrict__ W,
                                                   const int* __restrict__ idx,
                                                   float* __restrict__ q,
                                                   double* __restrict__ stats) {
    __shared__ float sW[COUT * CIN];
    __shared__ float sred[4][27];
    for (int i = threadIdx.x; i < COUT * CIN; i += 256) sW[i] = W[i];
    __syncthreads();

    int b = blockIdx.y;
    int n = blockIdx.x * 256 + threadIdx.x;
    const float* xb = x + (size_t)b * CIN * NPTS;
    const float4* p = pts + (size_t)b * NPTS;

    int nb[K_NN];
#pragma unroll
    for (int k = 0; k < K_NN; k++) nb[k] = idx[((size_t)b * K_NN + k) * NPTS + n];

    float f[CIN][K_NN];
#pragma unroll
    for (int k = 0; k < K_NN; k++) {
        float4 c = p[nb[k]];                    // xyz in one 16B gather (doubled)
        f[0][k] = 0.5f * c.x; f[1][k] = 0.5f * c.y; f[2][k] = 0.5f * c.z;
    }
#pragma unroll
    for (int c = 3; c < CIN; c++)
#pragma unroll
        for (int k = 0; k < K_NN; k++)
            f[c][k] = xb[c * NPTS + nb[k]];

    // center xyz over k, scale by 10
#pragma unroll
    for (int c = 0; c < 3; c++) {
        float s = 0.f;
#pragma unroll
        for (int k = 0; k < K_NN; k++) s += f[c][k];
        float m = s / 10.0f;
#pragma unroll
        for (int k = 0; k < K_NN; k++) f[c][k] = (f[c][k] - m) * 10.0f;
    }

    // q[b,o,n] = max_k y (BN affine + leaky are monotone -> applied in reduce)
    float* qb = q + (size_t)b * COUT * NPTS + n;
#pragma unroll
    for (int o = 0; o < COUT; o++) {
        float w0 = sW[o * 6 + 0], w1 = sW[o * 6 + 1], w2 = sW[o * 6 + 2];
        float w3 = sW[o * 6 + 3], w4 = sW[o * 6 + 4], w5 = sW[o * 6 + 5];
        float mx = -FLT_MAX;
#pragma unroll
        for (int k = 0; k < K_NN; k++) {
            float y = w0 * f[0][k] + w1 * f[1][k] + w2 * f[2][k] +
                      w3 * f[3][k] + w4 * f[4][k] + w5 * f[5][k];
            mx = fmaxf(mx, y);
        }
        qb[(size_t)o * NPTS] = mx;
    }

    // moment stats: S1[6], S2[21]
    float s1[CIN];
#pragma unroll
    for (int c = 0; c < CIN; c++) {
        float s = 0.f;
#pragma unroll
        for (int k = 0; k < K_NN; k++) s += f[c][k];
        s1[c] = s;
    }
    float s2[21];
#pragma unroll
    for (int i = 0; i < 21; i++) s2[i] = 0.f;
#pragma unroll
    for (int k = 0; k < K_NN; k++) {
        int pp = 0;
#pragma unroll
        for (int c = 0; c < CIN; c++)
#pragma unroll
            for (int c2 = c; c2 < CIN; c2++) {
                s2[pp] += f[c][k] * f[c2][k];
                pp++;
            }
    }
#pragma unroll
    for (int c = 0; c < CIN; c++) s1[c] = wave_sum(s1[c]);
#pragma unroll
    for (int i = 0; i < 21; i++) s2[i] = wave_sum(s2[i]);

    int wv = threadIdx.x >> 6;
    int ln = threadIdx.x & 63;
    if (ln == 0) {
#pragma unroll
        for (int c = 0; c < CIN; c++) sred[wv][c] = s1[c];
#pragma unroll
        for (int i = 0; i < 21; i++) sred[wv][6 + i] = s2[i];
    }
    __syncthreads();
    if (threadIdx.x < 27) {
        float t = sred[0][threadIdx.x] + sred[1][threadIdx.x] +
                  sred[2][threadIdx.x] + sred[3][threadIdx.x];
        atomicAdd(&stats[threadIdx.x], (double)t);
    }
}

// ---- Kernel C: fold moments -> scale/shift (in-block); leaky; reduce max+mean ----
__global__ __launch_bounds__(256) void reduce_kernel(const float* __restrict__ q,
                                                     const double* __restrict__ stats,
                                                     const float* __restrict__ W,
                                                     const float* __restrict__ gamma,
                                                     const float* __restrict__ beta,
                                                     float* __restrict__ out) {
    int o = blockIdx.x;
    int b = blockIdx.y;

    __shared__ float s_sc, s_sh;
    if (threadIdx.x == 0) {
        const double minv = 1.0 / (double)((size_t)BATCH * NPTS * K_NN);
        double w[CIN];
#pragma unroll
        for (int c = 0; c < CIN; c++) w[c] = (double)W[o * CIN + c];
        double mu = 0.0;
#pragma unroll
        for (int c = 0; c < CIN; c++) mu += w[c] * stats[c];
        mu *= minv;
        double ey2 = 0.0;
        int pp = 6;
#pragma unroll
        for (int c = 0; c < CIN; c++)
#pragma unroll
            for (int c2 = c; c2 < CIN; c2++) {
                double v = w[c] * w[c2] * stats[pp];
                ey2 += (c2 == c) ? v : 2.0 * v;
                pp++;
            }
        ey2 *= minv;
        double var = ey2 - mu * mu;
        float scale = gamma[o] * rsqrtf((float)var + BN_EPS);
        float shift = beta[o] - (float)mu * scale;
        s_sc = scale;
        s_sh = shift;
    }
    __syncthreads();
    float scale = s_sc, shift = s_sh;

    const float* qp = q + ((size_t)b * COUT + o) * NPTS;
    float mx = -FLT_MAX, sm = 0.f;
    for (int i = threadIdx.x; i < NPTS; i += 256) {
        float z = scale * qp[i] + shift;
        z = (z >= 0.f) ? z : NEG_SLOPE * z;
        mx = fmaxf(mx, z);
        sm += z;
    }
    mx = wave_max(mx);
    sm = wave_sum(sm);
    __shared__ float smx[4], ssm2[4];
    int wv = threadIdx.x >> 6;
    int ln = threadIdx.x & 63;
    if (ln == 0) { smx[wv] = mx; ssm2[wv] = sm; }
    __syncthreads();
    if (threadIdx.x == 0) {
        float m = fmaxf(fmaxf(smx[0], smx[1]), fmaxf(smx[2], smx[3]));
        float s = ssm2[0] + ssm2[1] + ssm2[2] + ssm2[3];
        out[b * 2 * COUT + o] = m;
        out[b * 2 * COUT + COUT + o] = s * (1.0f / (float)NPTS);
    }
}

extern "C" void kernel_launch(void* const* d_in, const int* in_sizes, int n_in,
                              void* d_out, int out_size, void* d_ws, size_t ws_size,
                              hipStream_t stream) {
    const float* x     = (const float*)d_in[0];
    const float* W     = (const float*)d_in[1];
    const float* gamma = (const float*)d_in[2];
    const float* beta  = (const float*)d_in[3];
    float* out = (float*)d_out;

    char* ws = (char*)d_ws;
    int*    idx   = (int*)(ws + OFF_IDX);
    float4* pts   = (float4*)(ws + OFF_PTS);
    int*    part  = (int*)(ws + OFF_Q);     // aliases q region (consumed before q written)
    float*  q     = (float*)(ws + OFF_Q);
    double* stats = (double*)(ws + OFF_ST);

    prep_pts<<<BATCH * NPTS / 256, 256, 0, stream>>>(x, pts, stats);
    knn_part<<<dim3(NPTS / QB, BATCH, NSEG), 256, 0, stream>>>(pts, part);
    merge_kernel<<<dim3(NPTS / 256, BATCH), 256, 0, stream>>>(pts, part, idx);
    feat_kernel<<<dim3(NPTS / 256, BATCH), 256, 0, stream>>>(pts, x, W, idx, q, stats);
    reduce_kernel<<<dim3(COUT, BATCH), 256, 0, stream>>>(q, stats, W, gamma, beta, out);
}